// Round 5
// baseline (96.834 us; speedup 1.0000x reference)
//
#include <hip/hip_runtime.h>

// CapsNet routing: N=32, C=32, D=16(=P*P), S=W*H=256, K=10, n_rout=3.
// 3 graph nodes (was 5): node-count dominates (measured ~11 us/node).
//  iter1 (mode 0): vec=g, write sp_a[n][c][160] non-atomic (no memset needed)
//  iter2 (mode 1): vec=squash(sum_c sp_a), write sp_b; zero s_fin+counter
//  iter3 (mode 2): vec=squash(sum_c sp_b), atomicAdd s_fin; last block per n
//                  (arrival counter, NO __threadfence -- R3 lesson) emits out.
// Ordering for last-block: atomic RMWs complete at the coherent point; the
// __syncthreads() before the counter add drains every wave's vmcnt.

#define KK 10
#define PP 16
#define CC 32
#define SS 256
#define NN 32

__global__ __launch_bounds__(256, 4) void iter_kernel(
    const float* __restrict__ l,       // [N][C][16][256]
    const float* __restrict__ w,       // [C][K][4][4]
    const float* __restrict__ g,       // [N][K][16]      (mode 0)
    const float* __restrict__ sp_in,   // [N][C][160]     (mode 1/2)
    float* __restrict__ sp_out,        // [N][C][160]     (mode 0/1)
    float* __restrict__ s_fin,         // [N][160]        (mode 1 zero, 2 accum)
    int* __restrict__ counter,         // [N]             (mode 1 zero, 2 arrive)
    float* __restrict__ out_a,         // [N][K]          (mode 2)
    float* __restrict__ out_gc,        // [N][K][16]      (mode 2)
    const int mode)
{
  const int bid = blockIdx.x;
  const int n = bid >> 5;
  const int c = bid & 31;
  const int t = threadIdx.x;           // t == s in phases 3-4

  __shared__ float lr_lds[PP][SS + 4];     // [ij][s]
  __shared__ float ct[KK][SS + 4];         // softmax weights [k][s]
  __shared__ float U_lds[KK * PP];         // U; reused for M, then s
  __shared__ float w_lds[KK * PP];         // w[c]
  __shared__ float gc_lds[KK * PP];        // g or squash(reduced sp_in)
  __shared__ float f_lds[KK];
  __shared__ float part[KK][PP][PP + 1];   // chunk partials of M
  __shared__ int   flag;

  // ---- stage w[c] and this block's l slice ----
  if (t < KK * PP) w_lds[t] = w[c * KK * PP + t];
  float lr[PP];
  const float* lb = l + (size_t)(n * CC + c) * (PP * SS) + t;
  #pragma unroll
  for (int d = 0; d < PP; ++d) {
    lr[d] = lb[d * SS];                 // coalesced across t
    lr_lds[d][t] = lr[d];
  }

  // ---- vec = g (mode 0) or squash(sum_c sp_in) (mode 1/2) ----
  if (mode == 0) {
    if (t < KK * PP) gc_lds[t] = g[n * KK * PP + t];
    __syncthreads();
  } else {
    if (t < KK * PP) {
      float sv = 0.f;
      #pragma unroll 8
      for (int c2 = 0; c2 < CC; ++c2)
        sv += sp_in[(n * CC + c2) * (KK * PP) + t];
      gc_lds[t] = sv;
    }
    if (mode == 1) {                       // zeroing duties for mode 2's pass
      if (c == 1 && t < KK * PP) s_fin[n * KK * PP + t] = 0.f;
      if (c == 2 && t == 0)      counter[n] = 0;
    }
    __syncthreads();
    if (t < KK) {
      float sn = 0.f;
      #pragma unroll
      for (int m = 0; m < PP; ++m) { const float v = gc_lds[t * PP + m]; sn += v * v; }
      f_lds[t] = sn / (1.f + sn) * rsqrtf(sn);
    }
    __syncthreads();
    if (t < KK * PP) gc_lds[t] *= f_lds[t >> 4];
    __syncthreads();
  }

  // ---- U[k][i*4+j] = sum_dd w[c,k,j,dd] * gc[k,i*4+dd] ----
  if (t < KK * PP) {
    const int k = t >> 4, ij = t & 15, i = ij >> 2, j = ij & 3;
    const float4 wv = *(const float4*)&w_lds[k * PP + j * 4];
    const float4 gv = *(const float4*)&gc_lds[k * PP + i * 4];
    U_lds[t] = wv.x * gv.x + wv.y * gv.y + wv.z * gv.z + wv.w * gv.w;
  }
  __syncthreads();

  // ---- b[k] = lr . U[k]; softmax over k; store ct[k][s] ----
  {
    float b[KK];
    float bmax = -1e30f;
    #pragma unroll
    for (int k = 0; k < KK; ++k) {
      float acc = 0.f;
      #pragma unroll
      for (int d4 = 0; d4 < 4; ++d4) {
        const float4 uv = *(const float4*)&U_lds[k * PP + d4 * 4];  // wave-uniform: LDS broadcast
        acc += lr[d4*4+0]*uv.x + lr[d4*4+1]*uv.y + lr[d4*4+2]*uv.z + lr[d4*4+3]*uv.w;
      }
      b[k] = acc;
      bmax = fmaxf(bmax, acc);
    }
    float ssum = 0.f;
    #pragma unroll
    for (int k = 0; k < KK; ++k) { b[k] = __expf(b[k] - bmax); ssum += b[k]; }
    const float inv = 1.f / ssum;
    #pragma unroll
    for (int k = 0; k < KK; ++k) ct[k][t] = b[k] * inv;
  }
  __syncthreads();

  // ---- M[k][ij] = sum_s ct[k][s]*lr[ij][s]: 256 thr, 16-s chunks ----
  {
    const int ch = t >> 4;        // 16 chunks of 16 s
    const int ij = t & 15;
    const int sbase = ch * 16;
    float acc[KK];
    #pragma unroll
    for (int k = 0; k < KK; ++k) acc[k] = 0.f;
    #pragma unroll
    for (int s4 = 0; s4 < 4; ++s4) {
      const float4 lv = *(const float4*)&lr_lds[ij][sbase + s4 * 4];
      #pragma unroll
      for (int k = 0; k < KK; ++k) {
        const float4 cv = *(const float4*)&ct[k][sbase + s4 * 4];
        acc[k] += cv.x*lv.x + cv.y*lv.y + cv.z*lv.z + cv.w*lv.w;
      }
    }
    #pragma unroll
    for (int k = 0; k < KK; ++k) part[k][ij][ch] = acc[k];
  }
  __syncthreads();

  // ---- merge chunk partials -> M (into U_lds) ----
  if (t < KK * PP) {
    const int k = t >> 4, ij = t & 15;
    float m = 0.f;
    #pragma unroll
    for (int s4 = 0; s4 < 4; ++s4) {
      const float4 pv = *(const float4*)&part[k][ij][s4 * 4];
      m += pv.x + pv.y + pv.z + pv.w;
    }
    U_lds[t] = m;   // U dead; now holds M
  }
  __syncthreads();

  // ---- s-partial[k][i*4+d] = sum_j M[k][i*4+j]*w[c,k,j,d] ----
  float sv = 0.f;
  if (t < KK * PP) {
    const int k = t >> 4, i = (t >> 2) & 3, d = t & 3;
    const float* Mp  = U_lds + k * PP + i * 4;
    const float* wpt = w_lds + k * PP + d;
    sv = Mp[0]*wpt[0] + Mp[1]*wpt[4] + Mp[2]*wpt[8] + Mp[3]*wpt[12];
  }

  if (mode != 2) {
    if (t < KK * PP) sp_out[(n * CC + c) * (KK * PP) + t] = sv;
    return;
  }

  // ---- mode 2: accumulate s, last block per n emits outputs ----
  if (t < KK * PP) atomicAdd(&s_fin[n * KK * PP + t], sv);
  __syncthreads();                       // drains all waves' vmcnt before barrier
  if (t == 0) flag = (atomicAdd(&counter[n], 1) == CC - 1);
  __syncthreads();
  if (!flag) return;

  if (t < KK * PP) U_lds[t] = atomicAdd(&s_fin[n * KK * PP + t], 0.f);  // coherent read
  __syncthreads();
  if (t < KK) {
    float sn = 0.f;
    #pragma unroll
    for (int m = 0; m < PP; ++m) { const float v = U_lds[t * PP + m]; sn += v * v; }
    f_lds[t] = sn / (1.f + sn) * rsqrtf(sn);
    const float gn = sn / (1.f + sn);    // = sqrt(sum gc^2)
    out_a[n * KK + t] = 1.f / (1.f + __expf(-gn));
  }
  __syncthreads();
  if (t < KK * PP) out_gc[n * KK * PP + t] = U_lds[t] * f_lds[t >> 4];
}

extern "C" void kernel_launch(void* const* d_in, const int* in_sizes, int n_in,
                              void* d_out, int out_size, void* d_ws, size_t ws_size,
                              hipStream_t stream) {
  const float* l = (const float*)d_in[0];
  const float* g = (const float*)d_in[1];
  const float* w = (const float*)d_in[2];

  float* out    = (float*)d_out;
  float* out_a  = out;
  float* out_gc = out + NN * KK;

  float* sp_a    = (float*)d_ws;                    // [N][C][160]
  float* sp_b    = sp_a + NN * CC * KK * PP;        // [N][C][160]
  float* s_fin   = sp_b + NN * CC * KK * PP;        // [N][160]
  int*   counter = (int*)(s_fin + NN * KK * PP);    // [N]

  iter_kernel<<<NN * CC, 256, 0, stream>>>(l, w, g, nullptr, sp_a,
                                           nullptr, nullptr, nullptr, nullptr, 0);
  iter_kernel<<<NN * CC, 256, 0, stream>>>(l, w, nullptr, sp_a, sp_b,
                                           s_fin, counter, nullptr, nullptr, 1);
  iter_kernel<<<NN * CC, 256, 0, stream>>>(l, w, nullptr, sp_b, nullptr,
                                           s_fin, counter, out_a, out_gc, 2);
}